// Round 7
// baseline (26.483 us; speedup 1.0000x reference)
//
#include <hip/hip_runtime.h>

typedef __fp16 h2 __attribute__((ext_vector_type(2)));

#define Hh 64
#define Ww 64

__device__ __forceinline__ h2 f2h2(float f) { return __builtin_bit_cast(h2, f); }

struct TapQ { float4 q0, q1, q2, q3; };

// Issue the 4 gather reads for one tap (pair-rows m and m+2, both n-halves).
__device__ __forceinline__ TapQ tap_issue(const float* Pf, int i, int m) {
    TapQ t;
    const int m2 = m + 2;
    const int d1 = (i * 14 + m)  * 8;
    const int d2 = (i * 14 + m2) * 8;
    const int s1 = m  & 4;
    const int s2 = m2 & 4;
    t.q0 = *(const float4*)(Pf + d1 + s1);
    t.q1 = *(const float4*)(Pf + d1 + (s1 ^ 4));
    t.q2 = *(const float4*)(Pf + d2 + s2);
    t.q3 = *(const float4*)(Pf + d2 + (s2 ^ 4));
    return t;
}

__device__ __forceinline__ void tap_mac(const TapQ& T, h2 w01, h2 w23, float* acc) {
    float qa[8] = {T.q0.x, T.q0.y, T.q0.z, T.q0.w, T.q1.x, T.q1.y, T.q1.z, T.q1.w};
    float qb[8] = {T.q2.x, T.q2.y, T.q2.z, T.q2.w, T.q3.x, T.q3.y, T.q3.z, T.q3.w};
    #pragma unroll
    for (int n = 0; n < 8; ++n) {
        acc[n] = __builtin_amdgcn_fdot2(w01, f2h2(qa[n]), acc[n], false);
        acc[n] = __builtin_amdgcn_fdot2(w23, f2h2(qb[n]), acc[n], false);
    }
}

// Wave = one 4-row x 64-col output strip of one (b,c) plane. Lane = column.
// LDS spline table PAIR-ROWS (f16, XOR-swizzled), tap = 4 ds_read_b128 + 16 fdot2.
// Taps pipelined in groups of 3 (12 loads in flight ahead of the MACs).
// Base path: f32 FMA against bw[] via uniform s_loads (no VGPR, no LDS).
__global__ __launch_bounds__(256, 3) void kan_conv_kernel(
    const float* __restrict__ x,     // (256, 64, 64)
    const float* __restrict__ bw,    // (8, 9)
    const float* __restrict__ sw,    // (8, 9, 8)
    const float* __restrict__ ss,    // (8, 9)
    float* __restrict__ out)         // (256, 8, 64, 64)
{
    __shared__ __align__(16) h2 Pl[9][14][8];

    const int tid = threadIdx.x;
    for (int idx = tid; idx < 9 * 14 * 8; idx += 256) {
        int i   = idx / 112;
        int rem = idx - i * 112;
        int g   = rem >> 3;
        int n   = rem & 7;
        const float sc = ss[n * 9 + i];
        float w0 = 0.f, w1 = 0.f;
        if (g >= 3 && g <= 10)         w0 = sw[(n * 9 + i) * 8 + (g - 3)] * sc;
        if (g + 1 >= 3 && g + 1 <= 10) w1 = sw[(n * 9 + i) * 8 + (g - 2)] * sc;
        h2 p; p.x = (__fp16)w0; p.y = (__fp16)w1;
        Pl[i][g][n ^ (g & 4)] = p;   // bank swizzle
    }
    __syncthreads();

    const int lane = tid & 63;
    const int wv   = tid >> 6;
    const int bc   = blockIdx.x >> 2;
    const int grp  = blockIdx.x & 3;
    const int r0   = grp * 16 + wv * 4;

    const float* __restrict__ xin = x + (size_t)bc * (Hh * Ww);
    float* __restrict__ op = out + (size_t)bc * (8 * Hh * Ww) + (size_t)r0 * Ww + lane;

    // rolling feature sets: [set][col]  col: 0=left,1=center,2=right
    float Fs[3][3];
    h2    Fw01[3][3];
    h2    Fw23[3][3];
    int   Fm[3][3];

    auto loadrow = [&](int y, int set) {
        float vC = 0.f, vL = 0.f, vR = 0.f;
        if ((unsigned)y < (unsigned)Hh) {
            const float* row = xin + y * Ww;
            vC = row[lane];
            vL = (lane == 0)  ? 0.f : row[lane - 1];
            vR = (lane == 63) ? 0.f : row[lane + 1];
        }
        float vv[3] = {vL, vC, vR};
        #pragma unroll
        for (int c = 0; c < 3; ++c) {
            float v = vv[c];
            float s = __fdividef(v, 1.f + __expf(-v));          // silu
            float u  = (v + 2.2f) * 2.5f;
            float mf = floorf(u);
            float t  = u - mf;
            int   m  = (int)mf;
            bool  inr = (m >= 0) && (m <= 10);
            m = min(max(m, 0), 10);
            float t2 = t * t, t3 = t2 * t, omt = 1.f - t;
            const float c6 = 1.f / 6.f;
            float w0 = c6 * omt * omt * omt;
            float w1 = c6 * (3.f * t3 - 6.f * t2 + 4.f);
            float w2 = c6 * (-3.f * t3 + 3.f * t2 + 3.f * t + 1.f);
            float w3 = c6 * t3;
            if (!inr) { w0 = 0.f; w1 = 0.f; w2 = 0.f; w3 = 0.f; }
            Fs[set][c]   = s;
            Fw01[set][c] = __builtin_amdgcn_cvt_pkrtz(w0, w1);
            Fw23[set][c] = __builtin_amdgcn_cvt_pkrtz(w2, w3);
            Fm[set][c]   = m;
        }
    };

    loadrow(r0 - 1, 0);
    loadrow(r0,     1);

    const float* __restrict__ Pf = (const float*)Pl;

    #pragma unroll
    for (int rr = 0; rr < 4; ++rr) {
        loadrow(r0 + rr + 1, (rr + 2) % 3);

        float acc[8];
        #pragma unroll
        for (int n = 0; n < 8; ++n) acc[n] = 0.f;

        const int sA = (rr + 0) % 3;
        const int sB = (rr + 1) % 3;
        const int sC = (rr + 2) % 3;

        // ---- pipelined spline path: issue 2 groups ahead, then steady ----
        TapQ A0 = tap_issue(Pf, 0, Fm[sA][0]);
        TapQ A1 = tap_issue(Pf, 1, Fm[sA][1]);
        TapQ A2 = tap_issue(Pf, 2, Fm[sA][2]);
        TapQ B0 = tap_issue(Pf, 3, Fm[sB][0]);
        TapQ B1 = tap_issue(Pf, 4, Fm[sB][1]);
        TapQ B2 = tap_issue(Pf, 5, Fm[sB][2]);

        tap_mac(A0, Fw01[sA][0], Fw23[sA][0], acc);
        tap_mac(A1, Fw01[sA][1], Fw23[sA][1], acc);
        tap_mac(A2, Fw01[sA][2], Fw23[sA][2], acc);

        TapQ C0 = tap_issue(Pf, 6, Fm[sC][0]);
        TapQ C1 = tap_issue(Pf, 7, Fm[sC][1]);
        TapQ C2 = tap_issue(Pf, 8, Fm[sC][2]);

        tap_mac(B0, Fw01[sB][0], Fw23[sB][0], acc);
        tap_mac(B1, Fw01[sB][1], Fw23[sB][1], acc);
        tap_mac(B2, Fw01[sB][2], Fw23[sB][2], acc);

        // ---- base path: f32 FMA with SGPR-resident base weights (covers C latency) ----
        #pragma unroll
        for (int ir = 0; ir < 3; ++ir) {
            const int set = (rr + ir) % 3;
            #pragma unroll
            for (int c = 0; c < 3; ++c) {
                const int i = ir * 3 + c;
                const float s = Fs[set][c];
                #pragma unroll
                for (int n = 0; n < 8; ++n)
                    acc[n] += s * bw[n * 9 + i];
            }
        }

        tap_mac(C0, Fw01[sC][0], Fw23[sC][0], acc);
        tap_mac(C1, Fw01[sC][1], Fw23[sC][1], acc);
        tap_mac(C2, Fw01[sC][2], Fw23[sC][2], acc);

        #pragma unroll
        for (int n = 0; n < 8; ++n)
            op[n * (Hh * Ww) + rr * Ww] = acc[n];
    }
}

extern "C" void kernel_launch(void* const* d_in, const int* in_sizes, int n_in,
                              void* d_out, int out_size, void* d_ws, size_t ws_size,
                              hipStream_t stream) {
    const float* x  = (const float*)d_in[0];
    const float* bw = (const float*)d_in[1];
    const float* sw = (const float*)d_in[2];
    const float* ss = (const float*)d_in[3];
    float* out = (float*)d_out;

    dim3 block(256, 1, 1);
    dim3 grid(1024, 1, 1);   // 256 bc * 4 strip-groups; wave = 4-row strip
    hipLaunchKernelGGL(kan_conv_kernel, grid, block, 0, stream, x, bw, sw, ss, out);
}